// Round 2
// baseline (170.146 us; speedup 1.0000x reference)
//
#include <hip/hip_runtime.h>
#include <math.h>

#define DEP   96
#define HEADS 96
#define BSZ   16
#define DIM   512
#define REL   128
#define RELP  129   // REL + nil

typedef __attribute__((ext_vector_type(8))) _Float16  half8;    // 8 fp16 (4 VGPRs)
typedef __attribute__((ext_vector_type(2))) __fp16    fp16x2;   // cvt_pkrtz return type
typedef __attribute__((ext_vector_type(4))) float     floatx4;

__device__ __forceinline__ unsigned short f2h(float x) {
    union { _Float16 h; unsigned short u; } c;
    c.h = (_Float16)x;                                   // v_cvt_f16_f32 (RNE)
    return c.u;
}
// two f32 -> packed 2xf16 in one v_cvt_pkrtz_f16_f32
__device__ __forceinline__ unsigned pk_f2h(float a, float b) {
    union { fp16x2 h; unsigned u; } c;
    c.h = __builtin_amdgcn_cvt_pkrtz(a, b);
    return c.u;
}
// packed fp16 add / relu (VOP3P)
__device__ __forceinline__ unsigned pk_add_h2(unsigned a, unsigned b) {
    unsigned r; asm("v_pk_add_f16 %0, %1, %2" : "=v"(r) : "v"(a), "v"(b)); return r;
}
__device__ __forceinline__ unsigned pk_max_h2(unsigned a, unsigned b) {
    unsigned r; asm("v_pk_max_f16 %0, %1, %2" : "=v"(r) : "v"(a), "v"(b)); return r;
}

#define PSS 72   // LDS row stride (fp16 elems): 144 B = 16B-aligned, ~2-way banks (free)

// ---------------------------------------------------------------------------
// Kernel A: projections via fp16 MFMA, T14 register-prefetch pipeline.
// Grid is only 384 blocks (1.5/CU) so latency must be hidden by ILP, not
// occupancy: next k-tile's A/Wt f32 loads are issued right after the
// stage-barrier and consumed (cast+ds_write) next iteration. Raw s_barrier
// (not __syncthreads) so the in-flight reg loads aren't vmcnt(0)-drained.
//   z=0: P1[m][n] = outs@Wt[:, :512]^T + bt   (f32 out)
//   z=1: P2H[m][n]= graph@Wt[:, 512:]^T       (fp16 out)
// First 32 blocks also cast Wp -> WpH (cvt_kernel stays eliminated).
// ---------------------------------------------------------------------------
__global__ __launch_bounds__(256) void proj_kernel(
    const float* __restrict__ outs, const float* __restrict__ graph,
    const float* __restrict__ Wt, const float* __restrict__ bt,
    const float* __restrict__ Wp,
    float* __restrict__ P1, unsigned short* __restrict__ P2H,
    unsigned short* __restrict__ WpH)
{
    // ---- Wp f32 -> fp16 prelude: 32 blocks x 256 thr ----
    {
        const int fb = (blockIdx.z * gridDim.y + blockIdx.y) * gridDim.x + blockIdx.x;
        if (fb < 32) {
            const int c = fb * 256 + (int)threadIdx.x;       // 0..8191 chunks of 8
            float4 a = *(const float4*)(Wp + (size_t)c * 8);
            float4 b = *(const float4*)(Wp + (size_t)c * 8 + 4);
            uint4 o;
            o.x = pk_f2h(a.x, a.y); o.y = pk_f2h(a.z, a.w);
            o.z = pk_f2h(b.x, b.y); o.w = pk_f2h(b.z, b.w);
            *(uint4*)(WpH + (size_t)c * 8) = o;
        }
    }

    const int z = blockIdx.z;
    const float* A = z ? graph : outs;
    const int off  = z ? DIM : 0;
    const int row0 = blockIdx.y * 64;
    const int col0 = blockIdx.x * 64;

    __shared__ __align__(16) unsigned short As[64 * PSS];   // [m][k] fp16
    __shared__ __align__(16) unsigned short Ws[64 * PSS];   // [n][k] fp16

    const int tid  = threadIdx.x;
    const int lane = tid & 63;
    const int wv   = tid >> 6;          // 0..3
    const int ln15 = lane & 15;
    const int quad = lane >> 4;
    const int e8   = (tid & 7) * 8;     // k-slot (elems), fixed per thread
    const int hb   = tid >> 3;          // 0..31 (row within 32-row group)

    const float* aBase = A  + (size_t)(row0 + hb) * DIM     + e8;
    const float* wBase = Wt + (size_t)(col0 + hb) * (2*DIM) + off + e8;

    // prologue: prefetch kt=0 into registers
    float4 va[2][2], wb[2][2];
    #pragma unroll
    for (int q = 0; q < 2; ++q) {
        const float* p = aBase + (size_t)q * 32 * DIM;
        va[q][0] = ((const float4*)p)[0]; va[q][1] = ((const float4*)p)[1];
        const float* w = wBase + (size_t)q * 32 * (2*DIM);
        wb[q][0] = ((const float4*)w)[0]; wb[q][1] = ((const float4*)w)[1];
    }

    floatx4 acc[4];
    #pragma unroll
    for (int nt = 0; nt < 4; ++nt) acc[nt] = (floatx4){0.f,0.f,0.f,0.f};

    for (int kt = 0; kt < DIM; kt += 64) {
        // cast + stage current tile (consumes va/wb; vmcnt waits auto-inserted)
        #pragma unroll
        for (int q = 0; q < 2; ++q) {
            uint4 o;
            o.x = pk_f2h(va[q][0].x, va[q][0].y); o.y = pk_f2h(va[q][0].z, va[q][0].w);
            o.z = pk_f2h(va[q][1].x, va[q][1].y); o.w = pk_f2h(va[q][1].z, va[q][1].w);
            *(uint4*)&As[(q*32 + hb) * PSS + e8] = o;
            uint4 u;
            u.x = pk_f2h(wb[q][0].x, wb[q][0].y); u.y = pk_f2h(wb[q][0].z, wb[q][0].w);
            u.z = pk_f2h(wb[q][1].x, wb[q][1].y); u.w = pk_f2h(wb[q][1].z, wb[q][1].w);
            *(uint4*)&Ws[(q*32 + hb) * PSS + e8] = u;
        }
        asm volatile("s_waitcnt lgkmcnt(0)" ::: "memory");
        __builtin_amdgcn_s_barrier();

        // issue next k-tile loads; latency hides under the MFMA phase below
        if (kt + 64 < DIM) {
            #pragma unroll
            for (int q = 0; q < 2; ++q) {
                const float* p = aBase + (size_t)q * 32 * DIM + kt + 64;
                va[q][0] = ((const float4*)p)[0]; va[q][1] = ((const float4*)p)[1];
                const float* w = wBase + (size_t)q * 32 * (2*DIM) + kt + 64;
                wb[q][0] = ((const float4*)w)[0]; wb[q][1] = ((const float4*)w)[1];
            }
        }

        #pragma unroll
        for (int ks = 0; ks < 64; ks += 32) {
            half8 af = *(const half8*)&As[(wv*16 + ln15) * PSS + ks + quad*8];
            #pragma unroll
            for (int nt = 0; nt < 4; ++nt) {
                half8 bf8 = *(const half8*)&Ws[(nt*16 + ln15) * PSS + ks + quad*8];
                acc[nt] = __builtin_amdgcn_mfma_f32_16x16x32_f16(af, bf8, acc[nt], 0, 0, 0);
            }
        }
        asm volatile("s_waitcnt lgkmcnt(0)" ::: "memory");
        __builtin_amdgcn_s_barrier();
    }

    #pragma unroll
    for (int nt = 0; nt < 4; ++nt) {
        #pragma unroll
        for (int reg = 0; reg < 4; ++reg) {
            const int m = row0 + wv*16 + quad*4 + reg;
            const int n = col0 + nt*16 + ln15;
            float v = acc[nt][reg];
            if (!z) P1[(size_t)m * DIM + n] = v + bt[n];
            else    P2H[(size_t)m * DIM + n] = f2h(v);
        }
    }
}

// ---------------------------------------------------------------------------
// Kernel B: fused pairwise relu + fp16-MFMA GEMM + log_softmax(129).
// REVERTED to 1 db/block (R1's 2-db pairing regressed: counters showed
// latency-bound, not LDS-bound; pairing cut the latency-hiding pool).
// NEW: T14 register-prefetch — next kt's P2H (3x uint4) + WpH (4x uint4)
// issued right after the stage-barrier, consumed next iteration. Raw
// s_barrier + lgkmcnt(0) so reg loads stay in flight across barriers.
// LDS 34.8 KB -> 4 blocks/CU; 1536 blocks.
// ---------------------------------------------------------------------------
#define HSS 72
#define WSS 72

__global__ __launch_bounds__(256, 4) void fused_kernel(
    const float* __restrict__ P1, const unsigned short* __restrict__ P2H,
    const unsigned short* __restrict__ WpH, const float* __restrict__ bp,
    float* __restrict__ out)
{
    const int db = blockIdx.x;      // d*16 + b
    const int b  = db & 15;

    __shared__ __align__(16) unsigned short drowH[DIM];     // dep row fp16
    __shared__ __align__(16) unsigned short hs[96 * HSS];   // h tile  [m][k]
    __shared__ __align__(16) unsigned short ws[128 * WSS];  // Wp tile [n][k]
    __shared__ float pmx[96][2];     // softmax partials per (row, col-half)
    __shared__ float pl [96][2];

    const int tid  = threadIdx.x;       // 0..255
    const int lane = tid & 63;
    const int wv   = tid >> 6;          // 0..3
    const int ln15 = lane & 15;
    const int quad = lane >> 4;
    const int mh   = wv & 1;            // row half: [48*mh, 48*mh+48)
    const int nh   = wv >> 1;           // col half: [64*nh, 64*nh+64)
    const int e8   = (tid & 7) * 8;     // k-slot, fixed per thread
    const int hb   = tid >> 3;          // 0..31

    // dep row f32 -> fp16 (one-time)
    {
        float2 v = *(const float2*)(P1 + (size_t)db * DIM + tid*2);
        *(unsigned*)&drowH[tid*2] = pk_f2h(v.x, v.y);
    }

    // prologue: prefetch kt=0 tiles into registers (before the barrier —
    // raw s_barrier does not drain vmcnt, loads stay in flight)
    const unsigned short* p2base = P2H + ((size_t)hb * BSZ + b) * DIM + e8;
    const unsigned short* wpbase = WpH + (size_t)hb * DIM + e8;
    uint4 pv[3], wr[4];
    #pragma unroll
    for (int q = 0; q < 3; ++q)
        pv[q] = *(const uint4*)(p2base + (size_t)q * 32 * BSZ * DIM);
    #pragma unroll
    for (int q = 0; q < 4; ++q)
        wr[q] = *(const uint4*)(wpbase + (size_t)q * 32 * DIM);

    asm volatile("s_waitcnt lgkmcnt(0)" ::: "memory");   // drowH writes drained
    __builtin_amdgcn_s_barrier();

    floatx4 acc[3][4];
    #pragma unroll
    for (int i = 0; i < 3; ++i)
        #pragma unroll
        for (int j = 0; j < 4; ++j) acc[i][j] = (floatx4){0.f,0.f,0.f,0.f};

    for (int kt = 0; kt < DIM; kt += 64) {
        uint4 dv = *(const uint4*)&drowH[kt + e8];
        // ---- stage hs[h][e] = fp16 relu(drow[e] + P2H[h,b,e]) from regs ----
        #pragma unroll
        for (int q = 0; q < 3; ++q) {
            uint4 o;
            o.x = pk_max_h2(pk_add_h2(pv[q].x, dv.x), 0u);
            o.y = pk_max_h2(pk_add_h2(pv[q].y, dv.y), 0u);
            o.z = pk_max_h2(pk_add_h2(pv[q].z, dv.z), 0u);
            o.w = pk_max_h2(pk_add_h2(pv[q].w, dv.w), 0u);
            *(uint4*)&hs[(q*32 + hb) * HSS + e8] = o;
        }
        // ---- stage ws[r][e] = WpH[r][kt+e] from regs ----
        #pragma unroll
        for (int q = 0; q < 4; ++q)
            *(uint4*)&ws[(q*32 + hb) * WSS + e8] = wr[q];

        asm volatile("s_waitcnt lgkmcnt(0)" ::: "memory");
        __builtin_amdgcn_s_barrier();

        // issue next-kt global loads; latency hides under the MFMA phase
        if (kt + 64 < DIM) {
            #pragma unroll
            for (int q = 0; q < 3; ++q)
                pv[q] = *(const uint4*)(p2base + (size_t)q * 32 * BSZ * DIM + kt + 64);
            #pragma unroll
            for (int q = 0; q < 4; ++q)
                wr[q] = *(const uint4*)(wpbase + (size_t)q * 32 * DIM + kt + 64);
        }

        #pragma unroll
        for (int ks = 0; ks < 64; ks += 32) {
            half8 af[3], bf[4];
            #pragma unroll
            for (int mt = 0; mt < 3; ++mt)
                af[mt] = *(const half8*)&hs[(mh*48 + mt*16 + ln15) * HSS + ks + quad*8];
            #pragma unroll
            for (int nt = 0; nt < 4; ++nt)
                bf[nt] = *(const half8*)&ws[(nh*64 + nt*16 + ln15) * WSS + ks + quad*8];
            #pragma unroll
            for (int nt = 0; nt < 4; ++nt)
                #pragma unroll
                for (int mt = 0; mt < 3; ++mt)
                    acc[mt][nt] = __builtin_amdgcn_mfma_f32_16x16x32_f16(
                        af[mt], bf[nt], acc[mt][nt], 0, 0, 0);
        }

        asm volatile("s_waitcnt lgkmcnt(0)" ::: "memory");
        __builtin_amdgcn_s_barrier();
    }

    // ---- epilogue phase 1: per-quadrant softmax partials (no nil yet) ----
    float bpv[4];
    #pragma unroll
    for (int nt = 0; nt < 4; ++nt) bpv[nt] = bp[nh*64 + nt*16 + ln15];

    #pragma unroll
    for (int mt = 0; mt < 3; ++mt) {
        #pragma unroll
        for (int reg = 0; reg < 4; ++reg) {
            const int m = mh*48 + mt*16 + quad*4 + reg;
            float s[4];
            float mx = -1e30f;
            #pragma unroll
            for (int nt = 0; nt < 4; ++nt) {
                s[nt] = acc[mt][nt][reg] + bpv[nt];
                mx = fmaxf(mx, s[nt]);
            }
            #pragma unroll
            for (int msk = 1; msk < 16; msk <<= 1) mx = fmaxf(mx, __shfl_xor(mx, msk));
            float l = 0.f;
            #pragma unroll
            for (int nt = 0; nt < 4; ++nt) l += __expf(s[nt] - mx);
            #pragma unroll
            for (int msk = 1; msk < 16; msk <<= 1) l += __shfl_xor(l, msk);
            if (ln15 == 0) { pmx[m][nh] = mx; pl[m][nh] = l; }
        }
    }
    __syncthreads();

    // ---- epilogue phase 2: combine halves + nil, write out ----
    #pragma unroll
    for (int mt = 0; mt < 3; ++mt) {
        #pragma unroll
        for (int reg = 0; reg < 4; ++reg) {
            const int m = mh*48 + mt*16 + quad*4 + reg;
            const float mx0 = pmx[m][0], mx1 = pmx[m][1];
            const float l0  = pl[m][0],  l1  = pl[m][1];
            const float MX = fmaxf(fmaxf(mx0, mx1), 0.f);   // nil = 0 in max
            const float L  = l0 * __expf(mx0 - MX) + l1 * __expf(mx1 - MX)
                           + __expf(-MX);                    // nil term
            const float lse = MX + __logf(L);

            const size_t base = ((size_t)db * HEADS + m) * RELP;
            #pragma unroll
            for (int nt = 0; nt < 4; ++nt)
                out[base + 1 + nh*64 + nt*16 + ln15] = acc[mt][nt][reg] + bpv[nt] - lse;
            if (nh == 0 && ln15 == 0) out[base] = -lse;
        }
    }
}

extern "C" void kernel_launch(void* const* d_in, const int* in_sizes, int n_in,
                              void* d_out, int out_size, void* d_ws, size_t ws_size,
                              hipStream_t stream) {
    const float* outs  = (const float*)d_in[0];
    const float* graph = (const float*)d_in[1];
    const float* Wt    = (const float*)d_in[2];
    const float* bt    = (const float*)d_in[3];
    const float* Wp    = (const float*)d_in[4];
    const float* bp    = (const float*)d_in[5];
    float* out = (float*)d_out;

    // Workspace: 4,849,664 B (WtH eliminated; Wt cast inline in proj).
    float* P1           = (float*)d_ws;                     // [1536][512] f32   (3 MB)
    unsigned short* P2H = (unsigned short*)(P1 + 786432);   // [1536][512] fp16  (1.5 MB)
    unsigned short* WpH = P2H + 786432;                     // [128][512]  fp16  (128 KB)

    proj_kernel<<<dim3(DIM/64, (DEP*BSZ)/64, 2), 256, 0, stream>>>(
        outs, graph, Wt, bt, Wp, P1, P2H, WpH);
    fused_kernel<<<DEP*BSZ, 256, 0, stream>>>(P1, P2H, WpH, bp, out);
}

// Round 3
// 145.408 us; speedup vs baseline: 1.1701x; 1.1701x over previous
//
#include <hip/hip_runtime.h>
#include <math.h>

#define DEP   96
#define HEADS 96
#define BSZ   16
#define DIM   512
#define REL   128
#define RELP  129   // REL + nil

typedef __attribute__((ext_vector_type(8))) _Float16  half8;    // 8 fp16 (4 VGPRs)
typedef __attribute__((ext_vector_type(2))) __fp16    fp16x2;   // cvt_pkrtz return type
typedef __attribute__((ext_vector_type(4))) float     floatx4;

typedef const __attribute__((address_space(1))) unsigned int* gas_t;
typedef __attribute__((address_space(3))) unsigned int*       las_t;

__device__ __forceinline__ unsigned short f2h(float x) {
    union { _Float16 h; unsigned short u; } c;
    c.h = (_Float16)x;                                   // v_cvt_f16_f32 (RNE)
    return c.u;
}
// two f32 -> packed 2xf16 in one v_cvt_pkrtz_f16_f32
__device__ __forceinline__ unsigned pk_f2h(float a, float b) {
    union { fp16x2 h; unsigned u; } c;
    c.h = __builtin_amdgcn_cvt_pkrtz(a, b);
    return c.u;
}
// packed fp16 add / relu (VOP3P)
__device__ __forceinline__ unsigned pk_add_h2(unsigned a, unsigned b) {
    unsigned r; asm("v_pk_add_f16 %0, %1, %2" : "=v"(r) : "v"(a), "v"(b)); return r;
}
__device__ __forceinline__ unsigned pk_max_h2(unsigned a, unsigned b) {
    unsigned r; asm("v_pk_max_f16 %0, %1, %2" : "=v"(r) : "v"(a), "v"(b)); return r;
}

#define PSS 72   // LDS row stride (fp16 elems): 144 B = 16B-aligned, ~2-way banks (free)

// ---------------------------------------------------------------------------
// Kernel A: projections via fp16 MFMA (R1 form — known good).
// Wt cast inline; first 32 blocks also cast Wp -> WpH as a prelude.
//   z=0: P1[m][n] = outs@Wt[:, :512]^T + bt   (f32 out)
//   z=1: P2H[m][n]= graph@Wt[:, 512:]^T       (fp16 out)
// 64x64 tile, BK=64, 256 threads = 4 waves.
// ---------------------------------------------------------------------------
__global__ __launch_bounds__(256) void proj_kernel(
    const float* __restrict__ outs, const float* __restrict__ graph,
    const float* __restrict__ Wt, const float* __restrict__ bt,
    const float* __restrict__ Wp,
    float* __restrict__ P1, unsigned short* __restrict__ P2H,
    unsigned short* __restrict__ WpH)
{
    // ---- Wp f32 -> fp16 prelude: 32 blocks x 256 thr ----
    {
        const int fb = (blockIdx.z * gridDim.y + blockIdx.y) * gridDim.x + blockIdx.x;
        if (fb < 32) {
            const int c = fb * 256 + (int)threadIdx.x;       // 0..8191 chunks of 8
            float4 a = *(const float4*)(Wp + (size_t)c * 8);
            float4 b = *(const float4*)(Wp + (size_t)c * 8 + 4);
            uint4 o;
            o.x = pk_f2h(a.x, a.y); o.y = pk_f2h(a.z, a.w);
            o.z = pk_f2h(b.x, b.y); o.w = pk_f2h(b.z, b.w);
            *(uint4*)(WpH + (size_t)c * 8) = o;
        }
    }

    const int z = blockIdx.z;
    const float* A = z ? graph : outs;
    const int off  = z ? DIM : 0;
    const int row0 = blockIdx.y * 64;
    const int col0 = blockIdx.x * 64;

    __shared__ __align__(16) unsigned short As[64 * PSS];   // [m][k] fp16
    __shared__ __align__(16) unsigned short Ws[64 * PSS];   // [n][k] fp16

    const int tid  = threadIdx.x;
    const int lane = tid & 63;
    const int wv   = tid >> 6;          // 0..3
    const int ln15 = lane & 15;
    const int quad = lane >> 4;

    floatx4 acc[4];
    #pragma unroll
    for (int nt = 0; nt < 4; ++nt) acc[nt] = (floatx4){0.f,0.f,0.f,0.f};

    for (int kt = 0; kt < DIM; kt += 64) {
        // A: f32 load + packed RTZ cast to fp16 LDS (8 elems/slot, 2 slots)
        #pragma unroll
        for (int q = 0; q < 2; ++q) {
            const int slot = q*256 + tid;       // 0..511
            const int r  = slot >> 3;           // 0..63
            const int e8 = (slot & 7) * 8;
            const float* p = A + (size_t)(row0 + r) * DIM + kt + e8;
            float4 va = *(const float4*)p;
            float4 vb = *(const float4*)(p + 4);
            uint4 o;
            o.x = pk_f2h(va.x, va.y); o.y = pk_f2h(va.z, va.w);
            o.z = pk_f2h(vb.x, vb.y); o.w = pk_f2h(vb.z, vb.w);
            *(uint4*)&As[r * PSS + e8] = o;
        }
        // Wt: f32 load + cast
        #pragma unroll
        for (int q = 0; q < 2; ++q) {
            const int slot = q*256 + tid;       // 0..511
            const int r  = slot >> 3;           // 0..63
            const int e8 = (slot & 7) * 8;
            const float* p = Wt + (size_t)(col0 + r) * (2*DIM) + off + kt + e8;
            float4 va = *(const float4*)p;
            float4 vb = *(const float4*)(p + 4);
            uint4 o;
            o.x = pk_f2h(va.x, va.y); o.y = pk_f2h(va.z, va.w);
            o.z = pk_f2h(vb.x, vb.y); o.w = pk_f2h(vb.z, vb.w);
            *(uint4*)&Ws[r * PSS + e8] = o;
        }
        __syncthreads();
        #pragma unroll
        for (int ks = 0; ks < 64; ks += 32) {
            half8 af = *(const half8*)&As[(wv*16 + ln15) * PSS + ks + quad*8];
            #pragma unroll
            for (int nt = 0; nt < 4; ++nt) {
                half8 bf8 = *(const half8*)&Ws[(nt*16 + ln15) * PSS + ks + quad*8];
                acc[nt] = __builtin_amdgcn_mfma_f32_16x16x32_f16(af, bf8, acc[nt], 0, 0, 0);
            }
        }
        __syncthreads();
    }

    #pragma unroll
    for (int nt = 0; nt < 4; ++nt) {
        #pragma unroll
        for (int reg = 0; reg < 4; ++reg) {
            const int m = row0 + wv*16 + quad*4 + reg;
            const int n = col0 + nt*16 + ln15;
            float v = acc[nt][reg];
            if (!z) P1[(size_t)m * DIM + n] = v + bt[n];
            else    P2H[(size_t)m * DIM + n] = f2h(v);
        }
    }
}

// ---------------------------------------------------------------------------
// Kernel B: fused pairwise relu + fp16-MFMA GEMM + log_softmax(129).
// R0 structure (1 db/block, __syncthreads — R1 pairing and R2 asm-pipeline
// both regressed: R1 cut the latency-hiding pool, R2 spilled to scratch).
// NEW: ws (Wp tile, pure copy) staged via __builtin_amdgcn_global_load_lds
// (async 16B DMA, no VGPR round-trip, no VALU) issued BEFORE the hs
// relu-staging so the DMA overlaps it. Linear [128][64] LDS dest (DMA
// requires it) + both-sides XOR swizzle (rule #21): source column
// pre-swizzled by ((lane>>3)<<4), read addr XORed with ((row&7)<<4)
// -> 2-way bank conflicts (free) instead of 16-way.
// LDS ~33.3 KB -> 4 blocks/CU; 1536 blocks.
// ---------------------------------------------------------------------------
#define HSS 72

__global__ __launch_bounds__(256, 4) void fused_kernel(
    const float* __restrict__ P1, const unsigned short* __restrict__ P2H,
    const unsigned short* __restrict__ WpH, const float* __restrict__ bp,
    float* __restrict__ out)
{
    const int db = blockIdx.x;      // d*16 + b
    const int b  = db & 15;

    __shared__ __align__(16) unsigned short drowH[DIM];     // dep row fp16
    __shared__ __align__(16) unsigned short hs[96 * HSS];   // h tile  [m][k] padded
    __shared__ __align__(16) unsigned short ws[128 * 64];   // Wp tile [n][k] linear+swz
    __shared__ float pmx[96][2];     // softmax partials per (row, col-half)
    __shared__ float pl [96][2];

    const int tid  = threadIdx.x;       // 0..255
    const int lane = tid & 63;
    const int wv   = tid >> 6;          // 0..3
    const int ln15 = lane & 15;
    const int quad = lane >> 4;
    const int mh   = wv & 1;            // row half: [48*mh, 48*mh+48)
    const int nh   = wv >> 1;           // col half: [64*nh, 64*nh+64)
    const int e8   = (tid & 7) * 8;     // k-slot (elems), fixed per thread
    const int hb   = tid >> 3;          // 0..31

    // DMA source swizzle: lane l deposits at ws_base + l*16 (HW rule) ->
    // row = rstart + (l>>3), colByte = (l&7)*16. Pre-swizzle the SOURCE
    // column so LDS holds WpH[row][col ^ ((row&7)<<4)].
    const int rgrp = lane >> 3;                       // 0..7 == row&7
    const int cswz = ((lane & 7) * 16) ^ (rgrp << 4); // swizzled col byte

    // dep row f32 -> fp16 (one-time)
    {
        float2 v = *(const float2*)(P1 + (size_t)db * DIM + tid*2);
        *(unsigned*)&drowH[tid*2] = pk_f2h(v.x, v.y);
    }
    __syncthreads();

    floatx4 acc[3][4];
    #pragma unroll
    for (int i = 0; i < 3; ++i)
        #pragma unroll
        for (int j = 0; j < 4; ++j) acc[i][j] = (floatx4){0.f,0.f,0.f,0.f};

    for (int kt = 0; kt < DIM; kt += 64) {
        // ---- ws: async DMA global->LDS, overlaps the hs staging below ----
        #pragma unroll
        for (int q = 0; q < 4; ++q) {
            const int rstart = q*32 + wv*8;           // wave-uniform
            const char* gp = (const char*)(WpH + (size_t)(rstart + rgrp) * DIM + kt) + cswz;
            __builtin_amdgcn_global_load_lds((gas_t)gp, (las_t)&ws[rstart * 64], 16, 0, 0);
        }
        // ---- stage hs[h][e] = fp16 relu(drow[e] + P2H[h,b,e]), 96x64 ----
        uint4 dv = *(const uint4*)&drowH[kt + e8];
        #pragma unroll
        for (int q = 0; q < 3; ++q) {
            const int h = q*32 + hb;                  // 0..95
            uint4 pv = *(const uint4*)(P2H + ((size_t)h * BSZ + b) * DIM + kt + e8);
            uint4 o;
            o.x = pk_max_h2(pk_add_h2(pv.x, dv.x), 0u);
            o.y = pk_max_h2(pk_add_h2(pv.y, dv.y), 0u);
            o.z = pk_max_h2(pk_add_h2(pv.z, dv.z), 0u);
            o.w = pk_max_h2(pk_add_h2(pv.w, dv.w), 0u);
            *(uint4*)&hs[h * HSS + e8] = o;
        }
        __syncthreads();   // drains vmcnt (DMA done) + lgkm (ds_writes done)

        #pragma unroll
        for (int ks = 0; ks < 64; ks += 32) {
            half8 af[3], bf[4];
            #pragma unroll
            for (int mt = 0; mt < 3; ++mt)
                af[mt] = *(const half8*)&hs[(mh*48 + mt*16 + ln15) * HSS + ks + quad*8];
            #pragma unroll
            for (int nt = 0; nt < 4; ++nt) {
                const int wrow = nh*64 + nt*16 + ln15;           // wrow&7 == ln15&7
                const int wb = wrow*128 + ((ks*2 + quad*16) ^ ((ln15 & 7) << 4));
                bf[nt] = *(const half8*)((const char*)ws + wb);
            }
            #pragma unroll
            for (int nt = 0; nt < 4; ++nt)
                #pragma unroll
                for (int mt = 0; mt < 3; ++mt)
                    acc[mt][nt] = __builtin_amdgcn_mfma_f32_16x16x32_f16(
                        af[mt], bf[nt], acc[mt][nt], 0, 0, 0);
        }
        __syncthreads();
    }

    // ---- epilogue phase 1: per-quadrant softmax partials (no nil yet) ----
    float bpv[4];
    #pragma unroll
    for (int nt = 0; nt < 4; ++nt) bpv[nt] = bp[nh*64 + nt*16 + ln15];

    #pragma unroll
    for (int mt = 0; mt < 3; ++mt) {
        #pragma unroll
        for (int reg = 0; reg < 4; ++reg) {
            const int m = mh*48 + mt*16 + quad*4 + reg;
            float s[4];
            float mx = -1e30f;
            #pragma unroll
            for (int nt = 0; nt < 4; ++nt) {
                s[nt] = acc[mt][nt][reg] + bpv[nt];
                mx = fmaxf(mx, s[nt]);
            }
            #pragma unroll
            for (int msk = 1; msk < 16; msk <<= 1) mx = fmaxf(mx, __shfl_xor(mx, msk));
            float l = 0.f;
            #pragma unroll
            for (int nt = 0; nt < 4; ++nt) l += __expf(s[nt] - mx);
            #pragma unroll
            for (int msk = 1; msk < 16; msk <<= 1) l += __shfl_xor(l, msk);
            if (ln15 == 0) { pmx[m][nh] = mx; pl[m][nh] = l; }
        }
    }
    __syncthreads();

    // ---- epilogue phase 2: combine halves + nil, write out ----
    #pragma unroll
    for (int mt = 0; mt < 3; ++mt) {
        #pragma unroll
        for (int reg = 0; reg < 4; ++reg) {
            const int m = mh*48 + mt*16 + quad*4 + reg;
            const float mx0 = pmx[m][0], mx1 = pmx[m][1];
            const float l0  = pl[m][0],  l1  = pl[m][1];
            const float MX = fmaxf(fmaxf(mx0, mx1), 0.f);   // nil = 0 in max
            const float L  = l0 * __expf(mx0 - MX) + l1 * __expf(mx1 - MX)
                           + __expf(-MX);                    // nil term
            const float lse = MX + __logf(L);

            const size_t base = ((size_t)db * HEADS + m) * RELP;
            #pragma unroll
            for (int nt = 0; nt < 4; ++nt)
                out[base + 1 + nh*64 + nt*16 + ln15] = acc[mt][nt][reg] + bpv[nt] - lse;
            if (nh == 0 && ln15 == 0) out[base] = -lse;
        }
    }
}

extern "C" void kernel_launch(void* const* d_in, const int* in_sizes, int n_in,
                              void* d_out, int out_size, void* d_ws, size_t ws_size,
                              hipStream_t stream) {
    const float* outs  = (const float*)d_in[0];
    const float* graph = (const float*)d_in[1];
    const float* Wt    = (const float*)d_in[2];
    const float* bt    = (const float*)d_in[3];
    const float* Wp    = (const float*)d_in[4];
    const float* bp    = (const float*)d_in[5];
    float* out = (float*)d_out;

    // Workspace: 4,849,664 B (WtH eliminated; Wt cast inline in proj).
    float* P1           = (float*)d_ws;                     // [1536][512] f32   (3 MB)
    unsigned short* P2H = (unsigned short*)(P1 + 786432);   // [1536][512] fp16  (1.5 MB)
    unsigned short* WpH = P2H + 786432;                     // [128][512]  fp16  (128 KB)

    proj_kernel<<<dim3(DIM/64, (DEP*BSZ)/64, 2), 256, 0, stream>>>(
        outs, graph, Wt, bt, Wp, P1, P2H, WpH);
    fused_kernel<<<DEP*BSZ, 256, 0, stream>>>(P1, P2H, WpH, bp, out);
}

// Round 4
// 142.799 us; speedup vs baseline: 1.1915x; 1.0183x over previous
//
#include <hip/hip_runtime.h>
#include <math.h>

#define DEP   96
#define HEADS 96
#define BSZ   16
#define DIM   512
#define REL   128
#define RELP  129   // REL + nil

typedef __attribute__((ext_vector_type(8))) _Float16  half8;    // 8 fp16 (4 VGPRs)
typedef __attribute__((ext_vector_type(2))) __fp16    fp16x2;   // cvt_pkrtz return type
typedef __attribute__((ext_vector_type(4))) float     floatx4;

__device__ __forceinline__ unsigned short f2h(float x) {
    union { _Float16 h; unsigned short u; } c;
    c.h = (_Float16)x;                                   // v_cvt_f16_f32 (RNE)
    return c.u;
}
// two f32 -> packed 2xf16 in one v_cvt_pkrtz_f16_f32
__device__ __forceinline__ unsigned pk_f2h(float a, float b) {
    union { fp16x2 h; unsigned u; } c;
    c.h = __builtin_amdgcn_cvt_pkrtz(a, b);
    return c.u;
}
// packed fp16 add / relu (VOP3P)
__device__ __forceinline__ unsigned pk_add_h2(unsigned a, unsigned b) {
    unsigned r; asm("v_pk_add_f16 %0, %1, %2" : "=v"(r) : "v"(a), "v"(b)); return r;
}
__device__ __forceinline__ unsigned pk_max_h2(unsigned a, unsigned b) {
    unsigned r; asm("v_pk_max_f16 %0, %1, %2" : "=v"(r) : "v"(a), "v"(b)); return r;
}

#define PSS 72   // LDS row stride (fp16 elems): 144 B = 16B-aligned, ~2-way banks (free)

// ---------------------------------------------------------------------------
// Kernel A: projections via fp16 MFMA (unchanged — measured healthy).
// Wt cast inline; first 32 blocks also cast Wp -> WpH as a prelude.
//   z=0: P1[m][n] = outs@Wt[:, :512]^T + bt   (f32 out)
//   z=1: P2H[m][n]= graph@Wt[:, 512:]^T       (fp16 out)
// ---------------------------------------------------------------------------
__global__ __launch_bounds__(256) void proj_kernel(
    const float* __restrict__ outs, const float* __restrict__ graph,
    const float* __restrict__ Wt, const float* __restrict__ bt,
    const float* __restrict__ Wp,
    float* __restrict__ P1, unsigned short* __restrict__ P2H,
    unsigned short* __restrict__ WpH)
{
    // ---- Wp f32 -> fp16 prelude: 32 blocks x 256 thr ----
    {
        const int fb = (blockIdx.z * gridDim.y + blockIdx.y) * gridDim.x + blockIdx.x;
        if (fb < 32) {
            const int c = fb * 256 + (int)threadIdx.x;       // 0..8191 chunks of 8
            float4 a = *(const float4*)(Wp + (size_t)c * 8);
            float4 b = *(const float4*)(Wp + (size_t)c * 8 + 4);
            uint4 o;
            o.x = pk_f2h(a.x, a.y); o.y = pk_f2h(a.z, a.w);
            o.z = pk_f2h(b.x, b.y); o.w = pk_f2h(b.z, b.w);
            *(uint4*)(WpH + (size_t)c * 8) = o;
        }
    }

    const int z = blockIdx.z;
    const float* A = z ? graph : outs;
    const int off  = z ? DIM : 0;
    const int row0 = blockIdx.y * 64;
    const int col0 = blockIdx.x * 64;

    __shared__ __align__(16) unsigned short As[64 * PSS];   // [m][k] fp16
    __shared__ __align__(16) unsigned short Ws[64 * PSS];   // [n][k] fp16

    const int tid  = threadIdx.x;
    const int lane = tid & 63;
    const int wv   = tid >> 6;          // 0..3
    const int ln15 = lane & 15;
    const int quad = lane >> 4;

    floatx4 acc[4];
    #pragma unroll
    for (int nt = 0; nt < 4; ++nt) acc[nt] = (floatx4){0.f,0.f,0.f,0.f};

    for (int kt = 0; kt < DIM; kt += 64) {
        // A: f32 load + packed RTZ cast to fp16 LDS (8 elems/slot, 2 slots)
        #pragma unroll
        for (int q = 0; q < 2; ++q) {
            const int slot = q*256 + tid;       // 0..511
            const int r  = slot >> 3;           // 0..63
            const int e8 = (slot & 7) * 8;
            const float* p = A + (size_t)(row0 + r) * DIM + kt + e8;
            float4 va = *(const float4*)p;
            float4 vb = *(const float4*)(p + 4);
            uint4 o;
            o.x = pk_f2h(va.x, va.y); o.y = pk_f2h(va.z, va.w);
            o.z = pk_f2h(vb.x, vb.y); o.w = pk_f2h(vb.z, vb.w);
            *(uint4*)&As[r * PSS + e8] = o;
        }
        // Wt: f32 load + cast
        #pragma unroll
        for (int q = 0; q < 2; ++q) {
            const int slot = q*256 + tid;       // 0..511
            const int r  = slot >> 3;           // 0..63
            const int e8 = (slot & 7) * 8;
            const float* p = Wt + (size_t)(col0 + r) * (2*DIM) + off + kt + e8;
            float4 va = *(const float4*)p;
            float4 vb = *(const float4*)(p + 4);
            uint4 o;
            o.x = pk_f2h(va.x, va.y); o.y = pk_f2h(va.z, va.w);
            o.z = pk_f2h(vb.x, vb.y); o.w = pk_f2h(vb.z, vb.w);
            *(uint4*)&Ws[r * PSS + e8] = o;
        }
        __syncthreads();
        #pragma unroll
        for (int ks = 0; ks < 64; ks += 32) {
            half8 af = *(const half8*)&As[(wv*16 + ln15) * PSS + ks + quad*8];
            #pragma unroll
            for (int nt = 0; nt < 4; ++nt) {
                half8 bf8 = *(const half8*)&Ws[(nt*16 + ln15) * PSS + ks + quad*8];
                acc[nt] = __builtin_amdgcn_mfma_f32_16x16x32_f16(af, bf8, acc[nt], 0, 0, 0);
            }
        }
        __syncthreads();
    }

    #pragma unroll
    for (int nt = 0; nt < 4; ++nt) {
        #pragma unroll
        for (int reg = 0; reg < 4; ++reg) {
            const int m = row0 + wv*16 + quad*4 + reg;
            const int n = col0 + nt*16 + ln15;
            float v = acc[nt][reg];
            if (!z) P1[(size_t)m * DIM + n] = v + bt[n];
            else    P2H[(size_t)m * DIM + n] = f2h(v);
        }
    }
}

// ---------------------------------------------------------------------------
// Kernel B: fused pairwise relu + fp16-MFMA GEMM + log_softmax(129).
// K-loop: R0 structure verbatim (padded LDS, ds_write staging, __syncthreads;
// R1 pairing / R2 asm-pipeline / R3 DMA all regressed or were neutral).
// NEW epilogue (R4): evidence across R0-R3 shows fused stuck at ~1.6 TB/s
// effective write BW (fill kernel: 6 TB/s) — store-path-bound. Fix:
//   1. lse computed ONCE per row (96 threads) instead of 12x per thread.
//   2. output staged in LDS (two 48x129 f32 halves, reusing the dead
//      hs/ws arena) then streamed out as fully-contiguous float4 stores
//      (1 KB/wave-instr): 192 quarter-dense store instrs -> ~56 dense.
// Identical f32 arithmetic -> absmax unchanged.
// LDS: arena 31.5K + drow 1K + partials 1.9K = 35.2 KB -> 4 blocks/CU.
// ---------------------------------------------------------------------------
#define HSS 72
#define WSS 72

__global__ __launch_bounds__(256, 4) void fused_kernel(
    const float* __restrict__ P1, const unsigned short* __restrict__ P2H,
    const unsigned short* __restrict__ WpH, const float* __restrict__ bp,
    float* __restrict__ out)
{
    const int db = blockIdx.x;      // d*16 + b
    const int b  = db & 15;

    // arena: hs[96][HSS] + ws[128][WSS] fp16 during K-loop; 48x129 f32 outbuf
    // in the epilogue (24768 B <= 32256 B, region dead after last MFMA).
    __shared__ __align__(16) char arena[96*HSS*2 + 128*WSS*2];
    unsigned short* hs = (unsigned short*)arena;               // h tile  [m][k]
    unsigned short* ws = (unsigned short*)(arena + 96*HSS*2);  // Wp tile [n][k]
    float* outb = (float*)arena;                               // [48*129] epilogue

    __shared__ __align__(16) unsigned short drowH[DIM];     // dep row fp16
    __shared__ float pmx[96][2];     // softmax partials per (row, col-half)
    __shared__ float pl [96][2];
    __shared__ float lseS[96];       // per-row lse

    const int tid  = threadIdx.x;       // 0..255
    const int lane = tid & 63;
    const int wv   = tid >> 6;          // 0..3
    const int ln15 = lane & 15;
    const int quad = lane >> 4;
    const int mh   = wv & 1;            // row half: [48*mh, 48*mh+48)
    const int nh   = wv >> 1;            // col half: [64*nh, 64*nh+64)

    // dep row f32 -> fp16 (one-time)
    {
        float2 v = *(const float2*)(P1 + (size_t)db * DIM + tid*2);
        *(unsigned*)&drowH[tid*2] = pk_f2h(v.x, v.y);
    }
    __syncthreads();

    floatx4 acc[3][4];
    #pragma unroll
    for (int i = 0; i < 3; ++i)
        #pragma unroll
        for (int j = 0; j < 4; ++j) acc[i][j] = (floatx4){0.f,0.f,0.f,0.f};

    for (int kt = 0; kt < DIM; kt += 64) {
        // ---- stage hs[h][e] = fp16 relu(drow[e] + P2H[h,b,e]), 96x64 ----
        #pragma unroll
        for (int q = 0; q < 3; ++q) {
            const int slot = q*256 + tid;        // 0..767
            const int h  = slot >> 3;            // 0..95
            const int e8 = (slot & 7) * 8;
            uint4 pv = *(const uint4*)(P2H + ((size_t)h * BSZ + b) * DIM + kt + e8);
            uint4 dv = *(const uint4*)&drowH[kt + e8];
            uint4 o;
            o.x = pk_max_h2(pk_add_h2(pv.x, dv.x), 0u);
            o.y = pk_max_h2(pk_add_h2(pv.y, dv.y), 0u);
            o.z = pk_max_h2(pk_add_h2(pv.z, dv.z), 0u);
            o.w = pk_max_h2(pk_add_h2(pv.w, dv.w), 0u);
            *(uint4*)&hs[h * HSS + e8] = o;
        }
        // ---- stage ws[r][e] = WpH[r][kt+e], 128x64 (B-operand layout) ----
        #pragma unroll
        for (int q = 0; q < 4; ++q) {
            const int slot = q*256 + tid;        // 0..1023
            const int r = slot >> 3;
            const int g = (slot & 7) * 8;
            *(uint4*)&ws[r * WSS + g] =
                *(const uint4*)(WpH + (size_t)r * DIM + kt + g);
        }
        __syncthreads();

        #pragma unroll
        for (int ks = 0; ks < 64; ks += 32) {
            half8 af[3], bf[4];
            #pragma unroll
            for (int mt = 0; mt < 3; ++mt)
                af[mt] = *(const half8*)&hs[(mh*48 + mt*16 + ln15) * HSS + ks + quad*8];
            #pragma unroll
            for (int nt = 0; nt < 4; ++nt)
                bf[nt] = *(const half8*)&ws[(nh*64 + nt*16 + ln15) * WSS + ks + quad*8];
            #pragma unroll
            for (int nt = 0; nt < 4; ++nt)
                #pragma unroll
                for (int mt = 0; mt < 3; ++mt)
                    acc[mt][nt] = __builtin_amdgcn_mfma_f32_16x16x32_f16(
                        af[mt], bf[nt], acc[mt][nt], 0, 0, 0);
        }
        __syncthreads();
    }

    // ---- epilogue phase 1: per-quadrant softmax partials (no nil yet) ----
    float bpv[4];
    #pragma unroll
    for (int nt = 0; nt < 4; ++nt) bpv[nt] = bp[nh*64 + nt*16 + ln15];

    #pragma unroll
    for (int mt = 0; mt < 3; ++mt) {
        #pragma unroll
        for (int reg = 0; reg < 4; ++reg) {
            const int m = mh*48 + mt*16 + quad*4 + reg;
            float s[4];
            #pragma unroll
            for (int nt = 0; nt < 4; ++nt) s[nt] = acc[mt][nt][reg] + bpv[nt];
            float mx = fmaxf(fmaxf(s[0], s[1]), fmaxf(s[2], s[3]));
            #pragma unroll
            for (int msk = 1; msk < 16; msk <<= 1) mx = fmaxf(mx, __shfl_xor(mx, msk));
            float l = 0.f;
            #pragma unroll
            for (int nt = 0; nt < 4; ++nt) l += __expf(s[nt] - mx);
            #pragma unroll
            for (int msk = 1; msk < 16; msk <<= 1) l += __shfl_xor(l, msk);
            if (ln15 == 0) { pmx[m][nh] = mx; pl[m][nh] = l; }
        }
    }
    __syncthreads();

    // ---- phase 1.5: lse once per row (was 12x redundant per thread) ----
    if (tid < 96) {
        const float mx0 = pmx[tid][0], mx1 = pmx[tid][1];
        const float MX = fmaxf(fmaxf(mx0, mx1), 0.f);   // nil = 0 in max
        const float L  = pl[tid][0] * __expf(mx0 - MX) + pl[tid][1] * __expf(mx1 - MX)
                       + __expf(-MX);                    // nil term
        lseS[tid] = MX + __logf(L);
    }
    __syncthreads();

    // ---- phase 2: stage each 48-row half in LDS, stream out coalesced ----
    #pragma unroll
    for (int g = 0; g < 2; ++g) {
        if (mh == g) {
            #pragma unroll
            for (int mt = 0; mt < 3; ++mt) {
                #pragma unroll
                for (int reg = 0; reg < 4; ++reg) {
                    const int lrow = mt*16 + quad*4 + reg;      // 0..47
                    const float lse = lseS[g*48 + lrow];
                    #pragma unroll
                    for (int nt = 0; nt < 4; ++nt)
                        outb[lrow*RELP + 1 + nh*64 + nt*16 + ln15] =
                            acc[mt][nt][reg] + bpv[nt] - lse;
                    if (nh == 0 && ln15 == 0) outb[lrow*RELP] = -lse;
                }
            }
        }
        __syncthreads();
        // 48*129 = 6192 floats = 1548 float4, contiguous in out
        float4* gout = (float4*)(out + (size_t)db * (HEADS*RELP) + g * (48*RELP));
        const float4* lsrc = (const float4*)outb;
        for (int j = tid; j < 1548; j += 256)
            gout[j] = lsrc[j];
        __syncthreads();
    }
}

extern "C" void kernel_launch(void* const* d_in, const int* in_sizes, int n_in,
                              void* d_out, int out_size, void* d_ws, size_t ws_size,
                              hipStream_t stream) {
    const float* outs  = (const float*)d_in[0];
    const float* graph = (const float*)d_in[1];
    const float* Wt    = (const float*)d_in[2];
    const float* bt    = (const float*)d_in[3];
    const float* Wp    = (const float*)d_in[4];
    const float* bp    = (const float*)d_in[5];
    float* out = (float*)d_out;

    // Workspace: 4,849,664 B (WtH eliminated; Wt cast inline in proj).
    float* P1           = (float*)d_ws;                     // [1536][512] f32   (3 MB)
    unsigned short* P2H = (unsigned short*)(P1 + 786432);   // [1536][512] fp16  (1.5 MB)
    unsigned short* WpH = P2H + 786432;                     // [128][512]  fp16  (128 KB)

    proj_kernel<<<dim3(DIM/64, (DEP*BSZ)/64, 2), 256, 0, stream>>>(
        outs, graph, Wt, bt, Wp, P1, P2H, WpH);
    fused_kernel<<<DEP*BSZ, 256, 0, stream>>>(P1, P2H, WpH, bp, out);
}

// Round 5
// 141.666 us; speedup vs baseline: 1.2010x; 1.0080x over previous
//
#include <hip/hip_runtime.h>
#include <math.h>

#define DEP   96
#define HEADS 96
#define BSZ   16
#define DIM   512
#define REL   128
#define RELP  129   // REL + nil

typedef __attribute__((ext_vector_type(8))) _Float16  half8;    // 8 fp16 (4 VGPRs)
typedef __attribute__((ext_vector_type(2))) __fp16    fp16x2;   // cvt_pkrtz return type
typedef __attribute__((ext_vector_type(4))) float     floatx4;

__device__ __forceinline__ unsigned short f2h(float x) {
    union { _Float16 h; unsigned short u; } c;
    c.h = (_Float16)x;                                   // v_cvt_f16_f32 (RNE)
    return c.u;
}
// two f32 -> packed 2xf16 in one v_cvt_pkrtz_f16_f32
__device__ __forceinline__ unsigned pk_f2h(float a, float b) {
    union { fp16x2 h; unsigned u; } c;
    c.h = __builtin_amdgcn_cvt_pkrtz(a, b);
    return c.u;
}
// packed fp16 add / relu (VOP3P)
__device__ __forceinline__ unsigned pk_add_h2(unsigned a, unsigned b) {
    unsigned r; asm("v_pk_add_f16 %0, %1, %2" : "=v"(r) : "v"(a), "v"(b)); return r;
}
__device__ __forceinline__ unsigned pk_max_h2(unsigned a, unsigned b) {
    unsigned r; asm("v_pk_max_f16 %0, %1, %2" : "=v"(r) : "v"(a), "v"(b)); return r;
}

#define PSS 72   // LDS row stride (fp16 elems): 144 B = 16B-aligned, ~2-way banks (free)

// ---------------------------------------------------------------------------
// Kernel A: projections via fp16 MFMA.
// R5 RESTRUCTURE: evidence total ≈ 94.5µs + fused across R0-R4 puts proj at
// ~45µs (floor ~5µs). Old shape: 384 blocks = 1.5/CU — latency-starved, no
// co-resident blocks to hide the 8 serial load→cast→barrier→MFMA chains.
// New shape: 32x64 tiles, grid (8,48,2) = 768 blocks = 3 resident/CU
// (LDS 13.8 KB), 12 waves/CU, per-thread staging 4→3 slots.
//   z=0: P1[m][n] = outs@Wt[:, :512]^T + bt   (f32 out)
//   z=1: P2H[m][n]= graph@Wt[:, 512:]^T       (fp16 out)
// Wave (mh=wv&1, nh=wv>>1) owns the 16m x 32n quadrant.
// First 32 blocks also cast Wp -> WpH as a prelude.
// ---------------------------------------------------------------------------
__global__ __launch_bounds__(256) void proj_kernel(
    const float* __restrict__ outs, const float* __restrict__ graph,
    const float* __restrict__ Wt, const float* __restrict__ bt,
    const float* __restrict__ Wp,
    float* __restrict__ P1, unsigned short* __restrict__ P2H,
    unsigned short* __restrict__ WpH)
{
    // ---- Wp f32 -> fp16 prelude: 32 blocks x 256 thr ----
    {
        const int fb = (blockIdx.z * gridDim.y + blockIdx.y) * gridDim.x + blockIdx.x;
        if (fb < 32) {
            const int c = fb * 256 + (int)threadIdx.x;       // 0..8191 chunks of 8
            float4 a = *(const float4*)(Wp + (size_t)c * 8);
            float4 b = *(const float4*)(Wp + (size_t)c * 8 + 4);
            uint4 o;
            o.x = pk_f2h(a.x, a.y); o.y = pk_f2h(a.z, a.w);
            o.z = pk_f2h(b.x, b.y); o.w = pk_f2h(b.z, b.w);
            *(uint4*)(WpH + (size_t)c * 8) = o;
        }
    }

    const int z = blockIdx.z;
    const float* A = z ? graph : outs;
    const int off  = z ? DIM : 0;
    const int row0 = blockIdx.y * 32;
    const int col0 = blockIdx.x * 64;

    __shared__ __align__(16) unsigned short As[32 * PSS];   // [m][k] fp16
    __shared__ __align__(16) unsigned short Ws[64 * PSS];   // [n][k] fp16

    const int tid  = threadIdx.x;
    const int lane = tid & 63;
    const int wv   = tid >> 6;          // 0..3
    const int ln15 = lane & 15;
    const int quad = lane >> 4;
    const int mh   = wv & 1;            // m-half: rows [16*mh, 16*mh+16)
    const int nh   = wv >> 1;           // n-half: cols [32*nh, 32*nh+32)

    floatx4 acc[2];
    acc[0] = (floatx4){0.f,0.f,0.f,0.f};
    acc[1] = (floatx4){0.f,0.f,0.f,0.f};

    for (int kt = 0; kt < DIM; kt += 64) {
        // A: f32 load + packed RTZ cast to fp16 LDS (1 slot/thread: 32 rows x 8 slots)
        {
            const int r  = tid >> 3;            // 0..31
            const int e8 = (tid & 7) * 8;
            const float* p = A + (size_t)(row0 + r) * DIM + kt + e8;
            float4 va = *(const float4*)p;
            float4 vb = *(const float4*)(p + 4);
            uint4 o;
            o.x = pk_f2h(va.x, va.y); o.y = pk_f2h(va.z, va.w);
            o.z = pk_f2h(vb.x, vb.y); o.w = pk_f2h(vb.z, vb.w);
            *(uint4*)&As[r * PSS + e8] = o;
        }
        // Wt: f32 load + cast (2 slots/thread: 64 rows x 8 slots)
        #pragma unroll
        for (int q = 0; q < 2; ++q) {
            const int slot = q*256 + tid;       // 0..511
            const int r  = slot >> 3;           // 0..63
            const int e8 = (slot & 7) * 8;
            const float* p = Wt + (size_t)(col0 + r) * (2*DIM) + off + kt + e8;
            float4 va = *(const float4*)p;
            float4 vb = *(const float4*)(p + 4);
            uint4 o;
            o.x = pk_f2h(va.x, va.y); o.y = pk_f2h(va.z, va.w);
            o.z = pk_f2h(vb.x, vb.y); o.w = pk_f2h(vb.z, vb.w);
            *(uint4*)&Ws[r * PSS + e8] = o;
        }
        __syncthreads();
        #pragma unroll
        for (int ks = 0; ks < 64; ks += 32) {
            half8 af = *(const half8*)&As[(mh*16 + ln15) * PSS + ks + quad*8];
            #pragma unroll
            for (int nt = 0; nt < 2; ++nt) {
                half8 bf8 = *(const half8*)&Ws[(nh*32 + nt*16 + ln15) * PSS + ks + quad*8];
                acc[nt] = __builtin_amdgcn_mfma_f32_16x16x32_f16(af, bf8, acc[nt], 0, 0, 0);
            }
        }
        __syncthreads();
    }

    #pragma unroll
    for (int nt = 0; nt < 2; ++nt) {
        #pragma unroll
        for (int reg = 0; reg < 4; ++reg) {
            const int m = row0 + mh*16 + quad*4 + reg;
            const int n = col0 + nh*32 + nt*16 + ln15;
            float v = acc[nt][reg];
            if (!z) P1[(size_t)m * DIM + n] = v + bt[n];
            else    P2H[(size_t)m * DIM + n] = f2h(v);
        }
    }
}

// ---------------------------------------------------------------------------
// Kernel B: fused pairwise relu + fp16-MFMA GEMM + log_softmax(129).
// UNCHANGED from R4 (measured 48.1-48.4 µs; R1 pairing / R2 asm-pipeline /
// R3 DMA / R4 epilogue-coalescing all failed to move it — latency-bound).
// Single-variable round: only proj changes.
// ---------------------------------------------------------------------------
#define HSS 72
#define WSS 72

__global__ __launch_bounds__(256, 4) void fused_kernel(
    const float* __restrict__ P1, const unsigned short* __restrict__ P2H,
    const unsigned short* __restrict__ WpH, const float* __restrict__ bp,
    float* __restrict__ out)
{
    const int db = blockIdx.x;      // d*16 + b
    const int b  = db & 15;

    // arena: hs[96][HSS] + ws[128][WSS] fp16 during K-loop; 48x129 f32 outbuf
    // in the epilogue (24768 B <= 32256 B, region dead after last MFMA).
    __shared__ __align__(16) char arena[96*HSS*2 + 128*WSS*2];
    unsigned short* hs = (unsigned short*)arena;               // h tile  [m][k]
    unsigned short* ws = (unsigned short*)(arena + 96*HSS*2);  // Wp tile [n][k]
    float* outb = (float*)arena;                               // [48*129] epilogue

    __shared__ __align__(16) unsigned short drowH[DIM];     // dep row fp16
    __shared__ float pmx[96][2];     // softmax partials per (row, col-half)
    __shared__ float pl [96][2];
    __shared__ float lseS[96];       // per-row lse

    const int tid  = threadIdx.x;       // 0..255
    const int lane = tid & 63;
    const int wv   = tid >> 6;          // 0..3
    const int ln15 = lane & 15;
    const int quad = lane >> 4;
    const int mh   = wv & 1;            // row half: [48*mh, 48*mh+48)
    const int nh   = wv >> 1;           // col half: [64*nh, 64*nh+64)

    // dep row f32 -> fp16 (one-time)
    {
        float2 v = *(const float2*)(P1 + (size_t)db * DIM + tid*2);
        *(unsigned*)&drowH[tid*2] = pk_f2h(v.x, v.y);
    }
    __syncthreads();

    floatx4 acc[3][4];
    #pragma unroll
    for (int i = 0; i < 3; ++i)
        #pragma unroll
        for (int j = 0; j < 4; ++j) acc[i][j] = (floatx4){0.f,0.f,0.f,0.f};

    for (int kt = 0; kt < DIM; kt += 64) {
        // ---- stage hs[h][e] = fp16 relu(drow[e] + P2H[h,b,e]), 96x64 ----
        #pragma unroll
        for (int q = 0; q < 3; ++q) {
            const int slot = q*256 + tid;        // 0..767
            const int h  = slot >> 3;            // 0..95
            const int e8 = (slot & 7) * 8;
            uint4 pv = *(const uint4*)(P2H + ((size_t)h * BSZ + b) * DIM + kt + e8);
            uint4 dv = *(const uint4*)&drowH[kt + e8];
            uint4 o;
            o.x = pk_max_h2(pk_add_h2(pv.x, dv.x), 0u);
            o.y = pk_max_h2(pk_add_h2(pv.y, dv.y), 0u);
            o.z = pk_max_h2(pk_add_h2(pv.z, dv.z), 0u);
            o.w = pk_max_h2(pk_add_h2(pv.w, dv.w), 0u);
            *(uint4*)&hs[h * HSS + e8] = o;
        }
        // ---- stage ws[r][e] = WpH[r][kt+e], 128x64 (B-operand layout) ----
        #pragma unroll
        for (int q = 0; q < 4; ++q) {
            const int slot = q*256 + tid;        // 0..1023
            const int r = slot >> 3;
            const int g = (slot & 7) * 8;
            *(uint4*)&ws[r * WSS + g] =
                *(const uint4*)(WpH + (size_t)r * DIM + kt + g);
        }
        __syncthreads();

        #pragma unroll
        for (int ks = 0; ks < 64; ks += 32) {
            half8 af[3], bf[4];
            #pragma unroll
            for (int mt = 0; mt < 3; ++mt)
                af[mt] = *(const half8*)&hs[(mh*48 + mt*16 + ln15) * HSS + ks + quad*8];
            #pragma unroll
            for (int nt = 0; nt < 4; ++nt)
                bf[nt] = *(const half8*)&ws[(nh*64 + nt*16 + ln15) * WSS + ks + quad*8];
            #pragma unroll
            for (int nt = 0; nt < 4; ++nt)
                #pragma unroll
                for (int mt = 0; mt < 3; ++mt)
                    acc[mt][nt] = __builtin_amdgcn_mfma_f32_16x16x32_f16(
                        af[mt], bf[nt], acc[mt][nt], 0, 0, 0);
        }
        __syncthreads();
    }

    // ---- epilogue phase 1: per-quadrant softmax partials (no nil yet) ----
    float bpv[4];
    #pragma unroll
    for (int nt = 0; nt < 4; ++nt) bpv[nt] = bp[nh*64 + nt*16 + ln15];

    #pragma unroll
    for (int mt = 0; mt < 3; ++mt) {
        #pragma unroll
        for (int reg = 0; reg < 4; ++reg) {
            const int m = mh*48 + mt*16 + quad*4 + reg;
            float s[4];
            #pragma unroll
            for (int nt = 0; nt < 4; ++nt) s[nt] = acc[mt][nt][reg] + bpv[nt];
            float mx = fmaxf(fmaxf(s[0], s[1]), fmaxf(s[2], s[3]));
            #pragma unroll
            for (int msk = 1; msk < 16; msk <<= 1) mx = fmaxf(mx, __shfl_xor(mx, msk));
            float l = 0.f;
            #pragma unroll
            for (int nt = 0; nt < 4; ++nt) l += __expf(s[nt] - mx);
            #pragma unroll
            for (int msk = 1; msk < 16; msk <<= 1) l += __shfl_xor(l, msk);
            if (ln15 == 0) { pmx[m][nh] = mx; pl[m][nh] = l; }
        }
    }
    __syncthreads();

    // ---- phase 1.5: lse once per row (was 12x redundant per thread) ----
    if (tid < 96) {
        const float mx0 = pmx[tid][0], mx1 = pmx[tid][1];
        const float MX = fmaxf(fmaxf(mx0, mx1), 0.f);   // nil = 0 in max
        const float L  = pl[tid][0] * __expf(mx0 - MX) + pl[tid][1] * __expf(mx1 - MX)
                       + __expf(-MX);                    // nil term
        lseS[tid] = MX + __logf(L);
    }
    __syncthreads();

    // ---- phase 2: stage each 48-row half in LDS, stream out coalesced ----
    #pragma unroll
    for (int g = 0; g < 2; ++g) {
        if (mh == g) {
            #pragma unroll
            for (int mt = 0; mt < 3; ++mt) {
                #pragma unroll
                for (int reg = 0; reg < 4; ++reg) {
                    const int lrow = mt*16 + quad*4 + reg;      // 0..47
                    const float lse = lseS[g*48 + lrow];
                    #pragma unroll
                    for (int nt = 0; nt < 4; ++nt)
                        outb[lrow*RELP + 1 + nh*64 + nt*16 + ln15] =
                            acc[mt][nt][reg] + bpv[nt] - lse;
                    if (nh == 0 && ln15 == 0) outb[lrow*RELP] = -lse;
                }
            }
        }
        __syncthreads();
        // 48*129 = 6192 floats = 1548 float4, contiguous in out
        float4* gout = (float4*)(out + (size_t)db * (HEADS*RELP) + g * (48*RELP));
        const float4* lsrc = (const float4*)outb;
        for (int j = tid; j < 1548; j += 256)
            gout[j] = lsrc[j];
        __syncthreads();
    }
}

extern "C" void kernel_launch(void* const* d_in, const int* in_sizes, int n_in,
                              void* d_out, int out_size, void* d_ws, size_t ws_size,
                              hipStream_t stream) {
    const float* outs  = (const float*)d_in[0];
    const float* graph = (const float*)d_in[1];
    const float* Wt    = (const float*)d_in[2];
    const float* bt    = (const float*)d_in[3];
    const float* Wp    = (const float*)d_in[4];
    const float* bp    = (const float*)d_in[5];
    float* out = (float*)d_out;

    // Workspace: 4,849,664 B (WtH eliminated; Wt cast inline in proj).
    float* P1           = (float*)d_ws;                     // [1536][512] f32   (3 MB)
    unsigned short* P2H = (unsigned short*)(P1 + 786432);   // [1536][512] fp16  (1.5 MB)
    unsigned short* WpH = P2H + 786432;                     // [128][512]  fp16  (128 KB)

    proj_kernel<<<dim3(DIM/64, (DEP*BSZ)/32, 2), 256, 0, stream>>>(
        outs, graph, Wt, bt, Wp, P1, P2H, WpH);
    fused_kernel<<<DEP*BSZ, 256, 0, stream>>>(P1, P2H, WpH, bp, out);
}